// Round 3
// baseline (110.786 us; speedup 1.0000x reference)
//
#include <hip/hip_runtime.h>

namespace {

constexpr int D_DIM   = 512;
constexpr int ENT_LEN = 39;
constexpr int N_MOVES = 896;

typedef __attribute__((ext_vector_type(4))) float f32x4;

// ---- fused bf16 table row offsets (rows of 512 bf16 = 1 KB each) ----
constexpr int R_SP    = 0;                 // 1280 rows: W_species[r] + sum(all 9 biases)
constexpr int R_AB    = 1280;              // 320
constexpr int R_IT    = 1600;              // 1024
constexpr int R_MV    = 2624;              // 1792 (mv rows then pp rows)
constexpr int R_LV    = 4416;              // 101: bits(lv)@W_level + (lv/100)W_feats[0]
constexpr int R_HP    = 4517;              // 1024: bits(hp)@W_hp + (hp/1023)W_feats[1]
constexpr int R_VOL   = 5541;              // 4*256 pair tables + 16 single = 1040
constexpr int R_BST   = 6581;              // 3*169 pair tables + 13 single = 520
constexpr int R_GS    = 7101;              // 32: gender x status
constexpr int R_FLAGS = 7133;              // 32: cb,trap,newsw,faint,active bits
constexpr int R_TS    = 7165;              // 32: toxic x sleep
constexpr int R_TOTAL = 7197;
constexpr size_t WS_NEED = (size_t)R_TOTAL * D_DIM * sizeof(unsigned short);

__device__ inline unsigned short f2bf(float f) {      // round-to-nearest-even
    unsigned u = __float_as_uint(f);
    u += 0x7fffu + ((u >> 16) & 1u);
    return (unsigned short)(u >> 16);
}

// ---------------- table precompute: 1 row per block, 2 dims per thread ----------------
__global__ __launch_bounds__(256) void build_tables(
    const float* __restrict__ Wsp, const float* __restrict__ bsp,
    const float* __restrict__ Wab, const float* __restrict__ bab,
    const float* __restrict__ Wit, const float* __restrict__ bit_,
    const float* __restrict__ Wmv, const float* __restrict__ bmv,
    const float* __restrict__ Wlv, const float* __restrict__ blv,
    const float* __restrict__ Whp, const float* __restrict__ bhp,
    const float* __restrict__ Wvo, const float* __restrict__ bvo,
    const float* __restrict__ Wft, const float* __restrict__ bft,
    const float* __restrict__ Wbo, const float* __restrict__ bbo,
    unsigned short* __restrict__ T)
{
    const int r = blockIdx.x;
    const int d = threadIdx.x << 1;
    float vx = 0.f, vy = 0.f;
    auto add = [&](const float* W, int row, float s) {
        const float2 w = *reinterpret_cast<const float2*>(W + (size_t)row * D_DIM + d);
        vx = fmaf(s, w.x, vx); vy = fmaf(s, w.y, vy);
    };
    if (r < R_AB) {
        add(Wsp, r, 1.f);
        add(bsp, 0, 1.f); add(bab, 0, 1.f); add(bit_, 0, 1.f);
        add(bmv, 0, 1.f); add(blv, 0, 1.f); add(bhp, 0, 1.f);
        add(bvo, 0, 1.f); add(bft, 0, 1.f); add(bbo, 0, 1.f);
    } else if (r < R_IT) {
        add(Wab, r - R_AB, 1.f);
    } else if (r < R_MV) {
        add(Wit, r - R_IT, 1.f);
    } else if (r < R_LV) {
        add(Wmv, r - R_MV, 1.f);
    } else if (r < R_HP) {
        const int lv = r - R_LV;
        for (int b = 0; b < 7; ++b) if ((lv >> b) & 1) add(Wlv, b, 1.f);
        add(Wft, 0, (float)lv * (1.f / 100.f));
    } else if (r < R_VOL) {
        const int hp = r - R_HP;
        for (int b = 0; b < 10; ++b) if ((hp >> b) & 1) add(Whp, b, 1.f);
        add(Wft, 1, (float)hp * (1.f / 1023.f));
    } else if (r < R_BST) {
        const int rr = r - R_VOL;
        if (rr < 1024) {                       // pair table p: code = v[2p] | v[2p+1]<<4
            const int p = rr >> 8, code = rr & 255, va = code & 15, vb = code >> 4;
            for (int b = 0; b < 4; ++b) {
                if ((va >> b) & 1) add(Wvo, 8 * p + b, 1.f);
                if ((vb >> b) & 1) add(Wvo, 8 * p + 4 + b, 1.f);
            }
        } else {                               // single col 8
            const int code = rr - 1024;
            for (int b = 0; b < 4; ++b) if ((code >> b) & 1) add(Wvo, 32 + b, 1.f);
        }
    } else if (r < R_GS) {
        const int rr = r - R_BST;
        if (rr < 507) {                        // pair q: idx = (b2q+6) + 13*(b2q1+6)
            const int q = rr / 169, code = rr % 169, ba = code % 13, bb = code / 13;
            add(Wbo, 34 + 26 * q + ba, 1.f);
            add(Wbo, 34 + 26 * q + 13 + bb, 1.f);
            add(Wft, 2 + 2 * q, 0.5f * (float)(ba - 6));
            add(Wft, 3 + 2 * q, 0.5f * (float)(bb - 6));
        } else {                               // single boost 6
            const int code = rr - 507;
            add(Wbo, 34 + 78 + code, 1.f);
            add(Wft, 8, 0.5f * (float)(code - 6));
        }
    } else if (r < R_FLAGS) {
        const int code = r - R_GS;             // g*8 + s
        add(Wbo, code >> 3, 1.f);
        add(Wbo, 4 + (code & 7), 1.f);
    } else if (r < R_TS) {
        const int code = r - R_FLAGS;          // cb*16+tr*8+ns*4+fa*2+ac
        add(Wbo, 12 + ((code >> 4) & 1), 1.f);
        add(Wbo, 14 + ((code >> 3) & 1), 1.f);
        add(Wbo, 16 + ((code >> 2) & 1), 1.f);
        add(Wbo, 30 + ((code >> 1) & 1), 1.f);
        add(Wbo, 32 + (code & 1), 1.f);
    } else {
        const int code = r - R_TS;             // tox*4 + sl
        add(Wbo, 18 + (code >> 2), 1.f);
        add(Wbo, 26 + (code & 3), 1.f);
    }
    ushort2 o; o.x = f2bf(vx); o.y = f2bf(vy);
    *reinterpret_cast<ushort2*>(T + (size_t)r * D_DIM + d) = o;
}

// -------- main encode: 1 wave per (entity, D-half); half 0 waves first, then half 1 --------
// D-split keeps the live table working set at ~3.7 MB < 4 MB per-XCD L2.
__global__ __launch_bounds__(256) void encode_kernel(
    const int* __restrict__ ent, const unsigned short* __restrict__ T,
    float* __restrict__ out_emb, float* __restrict__ out_mask, int n)
{
    const int w = (blockIdx.x << 2) | (threadIdx.x >> 6);   // global wave id in [0, 2n)
    const int half = (w >= n) ? 1 : 0;
    const int e4 = w - (half ? n : 0);
    if (e4 >= n) return;
    const int e_idx = __builtin_amdgcn_readfirstlane(e4);   // wave-uniform -> SGPR
    const int t = threadIdx.x & 63;
    const int* __restrict__ e = ent + (size_t)e_idx * ENT_LEN;

    // lane covers 4 dims: d = half*256 + t*4; 8 bytes of bf16 per row
    const char* __restrict__ Tb =
        reinterpret_cast<const char*>(T) + (half << 9) + (t << 3);

    float a0 = 0.f, a1 = 0.f, a2 = 0.f, a3 = 0.f;

    auto ADD = [&](int row) {
        const uint2 u = *reinterpret_cast<const uint2*>(Tb + ((size_t)(unsigned)row << 10));
        a0 += __uint_as_float(u.x << 16);
        a1 += __uint_as_float(u.x & 0xffff0000u);
        a2 += __uint_as_float(u.y << 16);
        a3 += __uint_as_float(u.y & 0xffff0000u);
    };
    auto FMA = [&](int row, float s) {
        const uint2 u = *reinterpret_cast<const uint2*>(Tb + ((size_t)(unsigned)row << 10));
        a0 = fmaf(s, __uint_as_float(u.x << 16),         a0);
        a1 = fmaf(s, __uint_as_float(u.x & 0xffff0000u), a1);
        a2 = fmaf(s, __uint_as_float(u.y << 16),         a2);
        a3 = fmaf(s, __uint_as_float(u.y & 0xffff0000u), a3);
    };

    const int sp = e[0];
    ADD(R_SP + sp);                       // biases folded in here
    ADD(R_AB + e[1]);
    ADD(R_IT + e[2]);
    #pragma unroll
    for (int m = 0; m < 4; ++m) {
        const int mv = e[21 + m];
        ADD(R_MV + mv);
        FMA(R_MV + N_MOVES + mv, (float)e[25 + m] * (1.f / 1023.f));
    }
    ADD(R_LV + e[3]);
    ADD(R_HP + e[4]);
    #pragma unroll
    for (int p = 0; p < 4; ++p)
        ADD(R_VOL + (p << 8) + (e[30 + 2 * p] | (e[31 + 2 * p] << 4)));
    ADD(R_VOL + 1024 + e[38]);
    #pragma unroll
    for (int q = 0; q < 3; ++q)
        ADD(R_BST + q * 169 + (e[14 + 2 * q] + 6) + 13 * (e[15 + 2 * q] + 6));
    ADD(R_BST + 507 + e[20] + 6);
    ADD(R_GS + (e[5] << 3) + e[6]);
    ADD(R_FLAGS + (e[7] << 4) + (e[8] << 3) + (e[9] << 2) + (e[12] << 1) + e[13]);
    ADD(R_TS + (e[10] << 2) + e[11]);

    const float msk = (sp > 1) ? 1.f : 0.f;
    f32x4 o = {a0 * msk, a1 * msk, a2 * msk, a3 * msk};
    f32x4* op = reinterpret_cast<f32x4*>(out_emb + (size_t)e_idx * D_DIM + (half << 8)) + t;
    __builtin_nontemporal_store(o, op);   // keep the 131 MB write stream out of L2
    if (half == 0 && t == 0) out_mask[e_idx] = msk;
}

// ---------------- fallback (round-0 kernel) if workspace is too small ----------------
__global__ __launch_bounds__(256) void entity_encoder_fallback(
    const int*   __restrict__ ent,
    const float* __restrict__ W_species, const float* __restrict__ b_species,
    const float* __restrict__ W_ability, const float* __restrict__ b_ability,
    const float* __restrict__ W_item,    const float* __restrict__ b_item,
    const float* __restrict__ W_moveset, const float* __restrict__ b_moveset,
    const float* __restrict__ W_level,   const float* __restrict__ b_level,
    const float* __restrict__ W_hp,      const float* __restrict__ b_hp,
    const float* __restrict__ W_vol,     const float* __restrict__ b_vol,
    const float* __restrict__ W_feats,   const float* __restrict__ b_feats,
    const float* __restrict__ W_bool,    const float* __restrict__ b_bool,
    float* __restrict__ out_emb, float* __restrict__ out_mask, int n)
{
    const int e_idx = (blockIdx.x << 1) | (threadIdx.x >> 7);
    if (e_idx >= n) return;
    const int t = threadIdx.x & 127;
    const int d = t << 2;
    const int* __restrict__ e = ent + e_idx * ENT_LEN;
    float4 acc = make_float4(0.f, 0.f, 0.f, 0.f);
#define ADDROW(W, row) do {                                                        \
        const float4 v_ = *reinterpret_cast<const float4*>((W) + ((size_t)(row))*D_DIM + d); \
        acc.x += v_.x; acc.y += v_.y; acc.z += v_.z; acc.w += v_.w;                \
    } while (0)
#define FMAROW(W, row, s) do {                                                     \
        const float4 v_ = *reinterpret_cast<const float4*>((W) + ((size_t)(row))*D_DIM + d); \
        const float s_ = (s);                                                      \
        acc.x = fmaf(s_, v_.x, acc.x); acc.y = fmaf(s_, v_.y, acc.y);              \
        acc.z = fmaf(s_, v_.z, acc.z); acc.w = fmaf(s_, v_.w, acc.w);              \
    } while (0)
    const int sp = e[0];
    ADDROW(W_species, sp); ADDROW(W_ability, e[1]); ADDROW(W_item, e[2]);
    #pragma unroll
    for (int m = 0; m < 4; ++m) {
        const int mv = e[21 + m];
        ADDROW(W_moveset, mv);
        FMAROW(W_moveset, N_MOVES + mv, (float)e[25 + m] * (1.0f / 1023.0f));
    }
    const int lv = e[3];
    #pragma unroll
    for (int b = 0; b < 7; ++b) if ((lv >> b) & 1) ADDROW(W_level, b);
    const int hp = e[4];
    #pragma unroll
    for (int b = 0; b < 10; ++b) if ((hp >> b) & 1) ADDROW(W_hp, b);
    #pragma unroll
    for (int j = 0; j < 9; ++j) {
        const int v = e[30 + j];
        #pragma unroll
        for (int b = 0; b < 4; ++b) if ((v >> b) & 1) ADDROW(W_vol, j * 4 + b);
    }
    FMAROW(W_feats, 0, (float)lv * (1.0f / 100.0f));
    FMAROW(W_feats, 1, (float)hp * (1.0f / 1023.0f));
    #pragma unroll
    for (int i = 0; i < 7; ++i) FMAROW(W_feats, 2 + i, 0.5f * (float)e[14 + i]);
    ADDROW(W_bool, e[5]); ADDROW(W_bool, 4 + e[6]); ADDROW(W_bool, 12 + e[7]);
    ADDROW(W_bool, 14 + e[8]); ADDROW(W_bool, 16 + e[9]); ADDROW(W_bool, 18 + e[10]);
    ADDROW(W_bool, 26 + e[11]); ADDROW(W_bool, 30 + e[12]); ADDROW(W_bool, 32 + e[13]);
    #pragma unroll
    for (int i = 0; i < 7; ++i) ADDROW(W_bool, 34 + 13 * i + e[14 + i] + 6);
    ADDROW(b_species, 0); ADDROW(b_ability, 0); ADDROW(b_item, 0);
    ADDROW(b_moveset, 0); ADDROW(b_level, 0);   ADDROW(b_hp, 0);
    ADDROW(b_vol, 0);     ADDROW(b_feats, 0);   ADDROW(b_bool, 0);
#undef ADDROW
#undef FMAROW
    const bool mask = !(sp == 0 || sp == 1);
    if (!mask) acc = make_float4(0.f, 0.f, 0.f, 0.f);
    *reinterpret_cast<float4*>(out_emb + (size_t)e_idx * D_DIM + d) = acc;
    if (t == 0) out_mask[e_idx] = mask ? 1.0f : 0.0f;
}

} // namespace

extern "C" void kernel_launch(void* const* d_in, const int* in_sizes, int n_in,
                              void* d_out, int out_size, void* d_ws, size_t ws_size,
                              hipStream_t stream) {
    const int n = in_sizes[0] / ENT_LEN;

    const int*   ent  = (const int*)  d_in[0];
    const float* Wsp  = (const float*)d_in[1];
    const float* bsp  = (const float*)d_in[2];
    const float* Wab  = (const float*)d_in[3];
    const float* bab  = (const float*)d_in[4];
    const float* Wit  = (const float*)d_in[5];
    const float* bit_ = (const float*)d_in[6];
    const float* Wmv  = (const float*)d_in[7];
    const float* bmv  = (const float*)d_in[8];
    const float* Wlv  = (const float*)d_in[9];
    const float* blv  = (const float*)d_in[10];
    const float* Whp  = (const float*)d_in[11];
    const float* bhp  = (const float*)d_in[12];
    const float* Wvo  = (const float*)d_in[13];
    const float* bvo  = (const float*)d_in[14];
    const float* Wft  = (const float*)d_in[15];
    const float* bft  = (const float*)d_in[16];
    const float* Wbo  = (const float*)d_in[17];
    const float* bbo  = (const float*)d_in[18];

    float* out_emb  = (float*)d_out;
    float* out_mask = out_emb + (size_t)n * D_DIM;

    if (ws_size >= WS_NEED) {
        unsigned short* T = (unsigned short*)d_ws;
        build_tables<<<R_TOTAL, 256, 0, stream>>>(
            Wsp, bsp, Wab, bab, Wit, bit_, Wmv, bmv, Wlv, blv,
            Whp, bhp, Wvo, bvo, Wft, bft, Wbo, bbo, T);
        const int waves = 2 * n;                       // (entity, half) pairs
        encode_kernel<<<(waves + 3) / 4, 256, 0, stream>>>(ent, T, out_emb, out_mask, n);
    } else {
        entity_encoder_fallback<<<(n + 1) / 2, 256, 0, stream>>>(
            ent, Wsp, bsp, Wab, bab, Wit, bit_, Wmv, bmv, Wlv, blv,
            Whp, bhp, Wvo, bvo, Wft, bft, Wbo, bbo, out_emb, out_mask, n);
    }
}

// Round 4
// 85.132 us; speedup vs baseline: 1.3013x; 1.3013x over previous
//
#include <hip/hip_runtime.h>

namespace {

constexpr int D_DIM   = 512;
constexpr int ENT_LEN = 39;
constexpr int N_MOVES = 896;

typedef __attribute__((ext_vector_type(4))) float f32x4;

// ---- fused bf16 table row offsets (rows of 512 bf16 = 1 KB each) ----
constexpr int R_SP    = 0;                 // 1280 rows: W_species[r] + sum(all 9 biases)
constexpr int R_AB    = 1280;              // 320
constexpr int R_IT    = 1600;              // 1024
constexpr int R_MV    = 2624;              // 1792 (mv rows then pp rows)
constexpr int R_LV    = 4416;              // 101: bits(lv)@W_level + (lv/100)W_feats[0]
constexpr int R_HP    = 4517;              // 1024: bits(hp)@W_hp + (hp/1023)W_feats[1]
constexpr int R_VOL   = 5541;              // 4*256 pair tables + 16 single = 1040
constexpr int R_BST   = 6581;              // 3*169 pair tables + 13 single = 520
constexpr int R_GS    = 7101;              // 32: gender x status
constexpr int R_FLAGS = 7133;              // 32: cb,trap,newsw,faint,active bits
constexpr int R_TS    = 7165;              // 32: toxic x sleep
constexpr int R_TOTAL = 7197;
constexpr size_t WS_NEED = (size_t)R_TOTAL * D_DIM * sizeof(unsigned short);

__device__ inline unsigned short f2bf(float f) {      // round-to-nearest-even
    unsigned u = __float_as_uint(f);
    u += 0x7fffu + ((u >> 16) & 1u);
    return (unsigned short)(u >> 16);
}

// ---------------- table precompute: 1 row per block, 2 dims per thread ----------------
__global__ __launch_bounds__(256) void build_tables(
    const float* __restrict__ Wsp, const float* __restrict__ bsp,
    const float* __restrict__ Wab, const float* __restrict__ bab,
    const float* __restrict__ Wit, const float* __restrict__ bit_,
    const float* __restrict__ Wmv, const float* __restrict__ bmv,
    const float* __restrict__ Wlv, const float* __restrict__ blv,
    const float* __restrict__ Whp, const float* __restrict__ bhp,
    const float* __restrict__ Wvo, const float* __restrict__ bvo,
    const float* __restrict__ Wft, const float* __restrict__ bft,
    const float* __restrict__ Wbo, const float* __restrict__ bbo,
    unsigned short* __restrict__ T)
{
    const int r = blockIdx.x;
    const int d = threadIdx.x << 1;
    float vx = 0.f, vy = 0.f;
    auto add = [&](const float* W, int row, float s) {
        const float2 w = *reinterpret_cast<const float2*>(W + (size_t)row * D_DIM + d);
        vx = fmaf(s, w.x, vx); vy = fmaf(s, w.y, vy);
    };
    if (r < R_AB) {
        add(Wsp, r, 1.f);
        add(bsp, 0, 1.f); add(bab, 0, 1.f); add(bit_, 0, 1.f);
        add(bmv, 0, 1.f); add(blv, 0, 1.f); add(bhp, 0, 1.f);
        add(bvo, 0, 1.f); add(bft, 0, 1.f); add(bbo, 0, 1.f);
    } else if (r < R_IT) {
        add(Wab, r - R_AB, 1.f);
    } else if (r < R_MV) {
        add(Wit, r - R_IT, 1.f);
    } else if (r < R_LV) {
        add(Wmv, r - R_MV, 1.f);
    } else if (r < R_HP) {
        const int lv = r - R_LV;
        for (int b = 0; b < 7; ++b) if ((lv >> b) & 1) add(Wlv, b, 1.f);
        add(Wft, 0, (float)lv * (1.f / 100.f));
    } else if (r < R_VOL) {
        const int hp = r - R_HP;
        for (int b = 0; b < 10; ++b) if ((hp >> b) & 1) add(Whp, b, 1.f);
        add(Wft, 1, (float)hp * (1.f / 1023.f));
    } else if (r < R_BST) {
        const int rr = r - R_VOL;
        if (rr < 1024) {                       // pair table p: code = v[2p] | v[2p+1]<<4
            const int p = rr >> 8, code = rr & 255, va = code & 15, vb = code >> 4;
            for (int b = 0; b < 4; ++b) {
                if ((va >> b) & 1) add(Wvo, 8 * p + b, 1.f);
                if ((vb >> b) & 1) add(Wvo, 8 * p + 4 + b, 1.f);
            }
        } else {                               // single col 8
            const int code = rr - 1024;
            for (int b = 0; b < 4; ++b) if ((code >> b) & 1) add(Wvo, 32 + b, 1.f);
        }
    } else if (r < R_GS) {
        const int rr = r - R_BST;
        if (rr < 507) {                        // pair q: idx = (b2q+6) + 13*(b2q1+6)
            const int q = rr / 169, code = rr % 169, ba = code % 13, bb = code / 13;
            add(Wbo, 34 + 26 * q + ba, 1.f);
            add(Wbo, 34 + 26 * q + 13 + bb, 1.f);
            add(Wft, 2 + 2 * q, 0.5f * (float)(ba - 6));
            add(Wft, 3 + 2 * q, 0.5f * (float)(bb - 6));
        } else {                               // single boost 6
            const int code = rr - 507;
            add(Wbo, 34 + 78 + code, 1.f);
            add(Wft, 8, 0.5f * (float)(code - 6));
        }
    } else if (r < R_FLAGS) {
        const int code = r - R_GS;             // g*8 + s
        add(Wbo, code >> 3, 1.f);
        add(Wbo, 4 + (code & 7), 1.f);
    } else if (r < R_TS) {
        const int code = r - R_FLAGS;          // cb*16+tr*8+ns*4+fa*2+ac
        add(Wbo, 12 + ((code >> 4) & 1), 1.f);
        add(Wbo, 14 + ((code >> 3) & 1), 1.f);
        add(Wbo, 16 + ((code >> 2) & 1), 1.f);
        add(Wbo, 30 + ((code >> 1) & 1), 1.f);
        add(Wbo, 32 + (code & 1), 1.f);
    } else {
        const int code = r - R_TS;             // tox*4 + sl
        add(Wbo, 18 + (code >> 2), 1.f);
        add(Wbo, 26 + (code & 3), 1.f);
    }
    ushort2 o; o.x = f2bf(vx); o.y = f2bf(vy);
    *reinterpret_cast<ushort2*>(T + (size_t)r * D_DIM + d) = o;
}

// -------- main encode: 1 wave = 2 entities x one D-half --------
// lanes 0-31 -> entity A, lanes 32-63 -> entity B; dwordx4 loads (16B/lane).
// Half-0 waves dispatch first, then half-1: live table set ~3.7 MB < 4 MB/XCD L2.
__global__ __launch_bounds__(256) void encode_kernel(
    const int* __restrict__ ent, const unsigned short* __restrict__ T,
    float* __restrict__ out_emb, float* __restrict__ out_mask, int n)
{
    const int nPairs = (n + 1) >> 1;
    const int w = (blockIdx.x << 2) | (threadIdx.x >> 6);   // wave id in [0, 2*nPairs)
    const int half = (w >= nPairs) ? 1 : 0;
    const int p0 = w - (half ? nPairs : 0);
    if (p0 >= nPairs) return;
    const int pA = __builtin_amdgcn_readfirstlane(p0);
    const int eA = 2 * pA;
    const int eB = (eA + 1 < n) ? eA + 1 : eA;              // odd-n guard (benign dup)
    const int* __restrict__ ea = ent + (size_t)eA * ENT_LEN;
    const int* __restrict__ eb = ent + (size_t)eB * ENT_LEN;

    const int lane = threadIdx.x & 63;
    const unsigned lmask = (lane >= 32) ? 0xFFFFFFFFu : 0u;  // B-group mask
    const unsigned laneByte = ((unsigned)(lane & 31) << 4) + ((unsigned)half << 9);
    const char* __restrict__ Tb = reinterpret_cast<const char*>(T);

    // branchless per-lane select between the two wave-uniform values (exact for bits)
    auto SEL = [&](unsigned a, unsigned b) -> unsigned { return a + ((b - a) & lmask); };
    auto FSEL = [&](float a, float b) -> float {
        return __uint_as_float(SEL(__float_as_uint(a), __float_as_uint(b)));
    };
#define VOFF(rA_, rB_) ((SEL((unsigned)(rA_), (unsigned)(rB_)) << 10) + laneByte)

    float a0=0.f,a1=0.f,a2=0.f,a3=0.f,a4=0.f,a5=0.f,a6=0.f,a7=0.f;

    // hi half uses contaminated as_float(u) (low 16 bits = mantissa noise <= 2^-8 rel);
    // lo half exact via shift.
    auto ACC = [&](unsigned voff) {
        const uint4 u = *reinterpret_cast<const uint4*>(Tb + voff);
        a0 += __uint_as_float(u.x << 16);  a1 += __uint_as_float(u.x);
        a2 += __uint_as_float(u.y << 16);  a3 += __uint_as_float(u.y);
        a4 += __uint_as_float(u.z << 16);  a5 += __uint_as_float(u.z);
        a6 += __uint_as_float(u.w << 16);  a7 += __uint_as_float(u.w);
    };
    auto FMA = [&](unsigned voff, float s) {
        const uint4 u = *reinterpret_cast<const uint4*>(Tb + voff);
        a0 = fmaf(s, __uint_as_float(u.x << 16), a0);  a1 = fmaf(s, __uint_as_float(u.x), a1);
        a2 = fmaf(s, __uint_as_float(u.y << 16), a2);  a3 = fmaf(s, __uint_as_float(u.y), a3);
        a4 = fmaf(s, __uint_as_float(u.z << 16), a4);  a5 = fmaf(s, __uint_as_float(u.z), a5);
        a6 = fmaf(s, __uint_as_float(u.w << 16), a6);  a7 = fmaf(s, __uint_as_float(u.w), a7);
    };

    const int spA = ea[0], spB = eb[0];
    ACC(VOFF(R_SP + spA, R_SP + spB));                       // biases folded here
    ACC(VOFF(R_AB + ea[1], R_AB + eb[1]));
    ACC(VOFF(R_IT + ea[2], R_IT + eb[2]));
    #pragma unroll
    for (int m = 0; m < 4; ++m) {
        const int mvA = ea[21 + m], mvB = eb[21 + m];
        ACC(VOFF(R_MV + mvA, R_MV + mvB));
        const float sA = (float)ea[25 + m] * (1.f / 1023.f);
        const float sB = (float)eb[25 + m] * (1.f / 1023.f);
        FMA(VOFF(R_MV + N_MOVES + mvA, R_MV + N_MOVES + mvB), FSEL(sA, sB));
    }
    ACC(VOFF(R_LV + ea[3], R_LV + eb[3]));
    ACC(VOFF(R_HP + ea[4], R_HP + eb[4]));
    #pragma unroll
    for (int q = 0; q < 4; ++q)
        ACC(VOFF(R_VOL + (q << 8) + (ea[30 + 2*q] | (ea[31 + 2*q] << 4)),
                 R_VOL + (q << 8) + (eb[30 + 2*q] | (eb[31 + 2*q] << 4))));
    ACC(VOFF(R_VOL + 1024 + ea[38], R_VOL + 1024 + eb[38]));
    #pragma unroll
    for (int q = 0; q < 3; ++q)
        ACC(VOFF(R_BST + q*169 + (ea[14 + 2*q] + 6) + 13*(ea[15 + 2*q] + 6),
                 R_BST + q*169 + (eb[14 + 2*q] + 6) + 13*(eb[15 + 2*q] + 6)));
    ACC(VOFF(R_BST + 507 + ea[20] + 6, R_BST + 507 + eb[20] + 6));
    ACC(VOFF(R_GS + (ea[5] << 3) + ea[6], R_GS + (eb[5] << 3) + eb[6]));
    ACC(VOFF(R_FLAGS + (ea[7] << 4) + (ea[8] << 3) + (ea[9] << 2) + (ea[12] << 1) + ea[13],
             R_FLAGS + (eb[7] << 4) + (eb[8] << 3) + (eb[9] << 2) + (eb[12] << 1) + eb[13]));
    ACC(VOFF(R_TS + (ea[10] << 2) + ea[11], R_TS + (eb[10] << 2) + eb[11]));
#undef VOFF

    const int sp_l = (int)SEL((unsigned)spA, (unsigned)spB);
    const float msk = (sp_l > 1) ? 1.f : 0.f;
    const int e_l = (int)SEL((unsigned)eA, (unsigned)eB);

    f32x4 o0 = {a0*msk, a1*msk, a2*msk, a3*msk};
    f32x4 o1 = {a4*msk, a5*msk, a6*msk, a7*msk};
    // lane covers 8 consecutive f32 dims: d = half*256 + (lane&31)*8
    float* op = out_emb + (size_t)e_l * D_DIM + (half << 8) + ((lane & 31) << 3);
    __builtin_nontemporal_store(o0, reinterpret_cast<f32x4*>(op));
    __builtin_nontemporal_store(o1, reinterpret_cast<f32x4*>(op + 4));
    if (half == 0 && (lane & 31) == 0) out_mask[e_l] = msk;
}

// ---------------- fallback (round-0 kernel) if workspace is too small ----------------
__global__ __launch_bounds__(256) void entity_encoder_fallback(
    const int*   __restrict__ ent,
    const float* __restrict__ W_species, const float* __restrict__ b_species,
    const float* __restrict__ W_ability, const float* __restrict__ b_ability,
    const float* __restrict__ W_item,    const float* __restrict__ b_item,
    const float* __restrict__ W_moveset, const float* __restrict__ b_moveset,
    const float* __restrict__ W_level,   const float* __restrict__ b_level,
    const float* __restrict__ W_hp,      const float* __restrict__ b_hp,
    const float* __restrict__ W_vol,     const float* __restrict__ b_vol,
    const float* __restrict__ W_feats,   const float* __restrict__ b_feats,
    const float* __restrict__ W_bool,    const float* __restrict__ b_bool,
    float* __restrict__ out_emb, float* __restrict__ out_mask, int n)
{
    const int e_idx = (blockIdx.x << 1) | (threadIdx.x >> 7);
    if (e_idx >= n) return;
    const int t = threadIdx.x & 127;
    const int d = t << 2;
    const int* __restrict__ e = ent + e_idx * ENT_LEN;
    float4 acc = make_float4(0.f, 0.f, 0.f, 0.f);
#define ADDROW(W, row) do {                                                        \
        const float4 v_ = *reinterpret_cast<const float4*>((W) + ((size_t)(row))*D_DIM + d); \
        acc.x += v_.x; acc.y += v_.y; acc.z += v_.z; acc.w += v_.w;                \
    } while (0)
#define FMAROW(W, row, s) do {                                                     \
        const float4 v_ = *reinterpret_cast<const float4*>((W) + ((size_t)(row))*D_DIM + d); \
        const float s_ = (s);                                                      \
        acc.x = fmaf(s_, v_.x, acc.x); acc.y = fmaf(s_, v_.y, acc.y);              \
        acc.z = fmaf(s_, v_.z, acc.z); acc.w = fmaf(s_, v_.w, acc.w);              \
    } while (0)
    const int sp = e[0];
    ADDROW(W_species, sp); ADDROW(W_ability, e[1]); ADDROW(W_item, e[2]);
    #pragma unroll
    for (int m = 0; m < 4; ++m) {
        const int mv = e[21 + m];
        ADDROW(W_moveset, mv);
        FMAROW(W_moveset, N_MOVES + mv, (float)e[25 + m] * (1.0f / 1023.0f));
    }
    const int lv = e[3];
    #pragma unroll
    for (int b = 0; b < 7; ++b) if ((lv >> b) & 1) ADDROW(W_level, b);
    const int hp = e[4];
    #pragma unroll
    for (int b = 0; b < 10; ++b) if ((hp >> b) & 1) ADDROW(W_hp, b);
    #pragma unroll
    for (int j = 0; j < 9; ++j) {
        const int v = e[30 + j];
        #pragma unroll
        for (int b = 0; b < 4; ++b) if ((v >> b) & 1) ADDROW(W_vol, j * 4 + b);
    }
    FMAROW(W_feats, 0, (float)lv * (1.0f / 100.0f));
    FMAROW(W_feats, 1, (float)hp * (1.0f / 1023.0f));
    #pragma unroll
    for (int i = 0; i < 7; ++i) FMAROW(W_feats, 2 + i, 0.5f * (float)e[14 + i]);
    ADDROW(W_bool, e[5]); ADDROW(W_bool, 4 + e[6]); ADDROW(W_bool, 12 + e[7]);
    ADDROW(W_bool, 14 + e[8]); ADDROW(W_bool, 16 + e[9]); ADDROW(W_bool, 18 + e[10]);
    ADDROW(W_bool, 26 + e[11]); ADDROW(W_bool, 30 + e[12]); ADDROW(W_bool, 32 + e[13]);
    #pragma unroll
    for (int i = 0; i < 7; ++i) ADDROW(W_bool, 34 + 13 * i + e[14 + i] + 6);
    ADDROW(b_species, 0); ADDROW(b_ability, 0); ADDROW(b_item, 0);
    ADDROW(b_moveset, 0); ADDROW(b_level, 0);   ADDROW(b_hp, 0);
    ADDROW(b_vol, 0);     ADDROW(b_feats, 0);   ADDROW(b_bool, 0);
#undef ADDROW
#undef FMAROW
    const bool mask = !(sp == 0 || sp == 1);
    if (!mask) acc = make_float4(0.f, 0.f, 0.f, 0.f);
    *reinterpret_cast<float4*>(out_emb + (size_t)e_idx * D_DIM + d) = acc;
    if (t == 0) out_mask[e_idx] = mask ? 1.0f : 0.0f;
}

} // namespace

extern "C" void kernel_launch(void* const* d_in, const int* in_sizes, int n_in,
                              void* d_out, int out_size, void* d_ws, size_t ws_size,
                              hipStream_t stream) {
    const int n = in_sizes[0] / ENT_LEN;

    const int*   ent  = (const int*)  d_in[0];
    const float* Wsp  = (const float*)d_in[1];
    const float* bsp  = (const float*)d_in[2];
    const float* Wab  = (const float*)d_in[3];
    const float* bab  = (const float*)d_in[4];
    const float* Wit  = (const float*)d_in[5];
    const float* bit_ = (const float*)d_in[6];
    const float* Wmv  = (const float*)d_in[7];
    const float* bmv  = (const float*)d_in[8];
    const float* Wlv  = (const float*)d_in[9];
    const float* blv  = (const float*)d_in[10];
    const float* Whp  = (const float*)d_in[11];
    const float* bhp  = (const float*)d_in[12];
    const float* Wvo  = (const float*)d_in[13];
    const float* bvo  = (const float*)d_in[14];
    const float* Wft  = (const float*)d_in[15];
    const float* bft  = (const float*)d_in[16];
    const float* Wbo  = (const float*)d_in[17];
    const float* bbo  = (const float*)d_in[18];

    float* out_emb  = (float*)d_out;
    float* out_mask = out_emb + (size_t)n * D_DIM;

    if (ws_size >= WS_NEED) {
        unsigned short* T = (unsigned short*)d_ws;
        build_tables<<<R_TOTAL, 256, 0, stream>>>(
            Wsp, bsp, Wab, bab, Wit, bit_, Wmv, bmv, Wlv, blv,
            Whp, bhp, Wvo, bvo, Wft, bft, Wbo, bbo, T);
        const int nPairs = (n + 1) >> 1;
        const int waves  = 2 * nPairs;                 // (pair, half)
        encode_kernel<<<(waves + 3) / 4, 256, 0, stream>>>(ent, T, out_emb, out_mask, n);
    } else {
        entity_encoder_fallback<<<(n + 1) / 2, 256, 0, stream>>>(
            ent, Wsp, bsp, Wab, bab, Wit, bit_, Wmv, bmv, Wlv, blv,
            Whp, bhp, Wvo, bvo, Wft, bft, Wbo, bbo, out_emb, out_mask, n);
    }
}